// Round 6
// baseline (189.159 us; speedup 1.0000x reference)
//
#include <hip/hip_runtime.h>
#include <stdint.h>

static constexpr int B_ = 512, N_ = 32, D_ = 256, K_ = 8;
static constexpr int E1 = 40, E2 = 6;          // ee MLP dims 256->40->6->1
static constexpr int N1 = 81, N2 = 25, N3 = 8; // en MLP dims 256->81->25->8
static constexpr int XBP = 264;                // xs_h row stride (f16), 528 B, 16B-aligned
static constexpr int H1P = 72;                 // h1t row stride (f16), 144 B, 16B-aligned
static constexpr int HEP = 88;                 // h1e row stride (f16)
static constexpr float LN2f = 0.69314718055994530942f;

typedef float    f32x4 __attribute__((ext_vector_type(4)));
typedef _Float16 f16x8 __attribute__((ext_vector_type(8)));
typedef _Float16 f16x2 __attribute__((ext_vector_type(2)));
typedef uint32_t u32x4 __attribute__((ext_vector_type(4)));

union FragU { u32x4 d; f16x8 v; };
union PK2  { f16x2 h; uint32_t u; };

__device__ __forceinline__ float sspf(float x) {
    float ax = fabsf(x);
    float e  = __expf(-ax);
    return fmaxf(x, 0.f) + __logf(1.f + e) - LN2f;
}

// ---- prep: build fp16 MFMA B-fragment images in ws (run once per launch) ----
// ew1f: [3 Nt][8 Kt][64 lanes][4 dw]; nw1f: [6 Nt][8 Kt][64][4]; w2f: [2 Kt][64][4]
__global__ __launch_bounds__(256) void k_prep(
    const float* __restrict__ ew1, const float* __restrict__ ew2,
    const float* __restrict__ nw1,
    u32x4* __restrict__ ew1f, u32x4* __restrict__ nw1f, u32x4* __restrict__ w2f)
{
    const int wv = threadIdx.x >> 6, l = threadIdx.x & 63;
    const int quad = l >> 4, c = l & 15;
    const int w = blockIdx.x * 4 + wv;
    u32x4 d;
    if (w < 24) {                       // ew1 frag, Nt=w>>3, Kt=w&7
        int Nt = w >> 3, Kt = w & 7;
        int n = Nt * 16 + c;
        bool ok = (n < E1);
        #pragma unroll
        for (int d2 = 0; d2 < 4; ++d2) {
            int k0 = Kt * 32 + quad * 8 + 2 * d2;
            PK2 pk;
            pk.h[0] = (_Float16)(ok ? ew1[k0 * E1 + n] : 0.f);
            pk.h[1] = (_Float16)(ok ? ew1[(k0 + 1) * E1 + n] : 0.f);
            d[d2] = pk.u;
        }
        ew1f[w * 64 + l] = d;
    } else if (w < 72) {                // nw1 frag
        int idx = w - 24;
        int Nt = idx >> 3, Kt = idx & 7;
        int n = Nt * 16 + c;
        bool ok = (n < N1);
        #pragma unroll
        for (int d2 = 0; d2 < 4; ++d2) {
            int k0 = Kt * 32 + quad * 8 + 2 * d2;
            PK2 pk;
            pk.h[0] = (_Float16)(ok ? nw1[k0 * N1 + n] : 0.f);
            pk.h[1] = (_Float16)(ok ? nw1[(k0 + 1) * N1 + n] : 0.f);
            d[d2] = pk.u;
        }
        nw1f[idx * 64 + l] = d;
    } else if (w < 74) {                // ew2 frag, Kt=w-72
        int Kt = w - 72;
        #pragma unroll
        for (int d2 = 0; d2 < 4; ++d2) {
            int k0 = Kt * 32 + quad * 8 + 2 * d2;
            PK2 pk;
            pk.h[0] = (_Float16)((k0 < E1 && c < E2) ? ew2[k0 * E2 + c] : 0.f);
            pk.h[1] = (_Float16)((k0 + 1 < E1 && c < E2) ? ew2[(k0 + 1) * E2 + c] : 0.f);
            d[d2] = pk.u;
        }
        w2f[Kt * 64 + l] = d;
    }
}

// grid = 2*B_; block (b, p): p owns electrons i in [16p, 16p+16)
__global__ __launch_bounds__(256, 3) void k_fused(
    const float* __restrict__ rs, const float* __restrict__ xs,
    const float* __restrict__ coords,
    const u32x4* __restrict__ ew1f, const float* __restrict__ eb1,
    const u32x4* __restrict__ w2f, const float* __restrict__ eb2,
    const float* __restrict__ ew3, const float* __restrict__ eb3,
    const u32x4* __restrict__ nw1f, const float* __restrict__ nb1,
    const float* __restrict__ nw2, const float* __restrict__ nb2,
    const float* __restrict__ nw3, const float* __restrict__ nb3,
    float* __restrict__ out)
{
    __shared__ alignas(16) _Float16 xs_h[N_ * XBP];  // 16896 B, all 32 electrons
    __shared__ alignas(16) char uni[4 * 16 * H1P * 2]; // 9216 B union:
    // ee phase: h1t[4 waves][16][H1P] f16
    // en phase: h1e[16][HEP] f16 (2816 B) + h2e[16][26] f32 (1664 B)
    __shared__ float w_s[16 * N_];              // 2048 B, w[i_local][j]
    __shared__ float nw2_s[N1 * N2];            // 8100 B
    __shared__ float nw3_s[N2 * N3];
    __shared__ float rs_s[N_ * 3];
    __shared__ float nb2_s[N2];
    __shared__ float nb3_s[N3];
    __shared__ float co_s[K_ * 3];
    __shared__ float bfn_s[16 * 3];
    __shared__ float cut_s[16];

    _Float16* h1e = (_Float16*)uni;             // [16][HEP]
    float*    h2e = (float*)(uni + 16 * HEP * 2); // [16][26]

    const int b = blockIdx.x >> 1, p = blockIdx.x & 1;
    const int t = threadIdx.x;
    const int wv = t >> 6, l = t & 63, quad = l >> 4, c = l & 15;

    // ---- weight fragments: coalesced global loads (no LDS dependency) ----
    f16x8 b1f[3][8];   // ee W1 [256][40->48], 96 VGPRs
    #pragma unroll
    for (int Nt = 0; Nt < 3; ++Nt)
        #pragma unroll
        for (int Kt = 0; Kt < 8; ++Kt) {
            FragU f; f.d = ew1f[(Nt * 8 + Kt) * 64 + l];
            b1f[Nt][Kt] = f.v;
        }
    f16x8 b2f[2];      // ee W2 [40->64][6->16]
    #pragma unroll
    for (int Kt = 0; Kt < 2; ++Kt) {
        FragU f; f.d = w2f[Kt * 64 + l];
        b2f[Kt] = f.v;
    }
    float eb1v[3];
    #pragma unroll
    for (int Nt = 0; Nt < 3; ++Nt) { int n = Nt * 16 + c; eb1v[Nt] = (n < E1) ? eb1[n] : 0.f; }
    const float eb2v = (c < E2) ? eb2[c] : 0.f;
    const float w3v  = (c < E2) ? ew3[c] : 0.f;
    const float eb3v = eb3[0];

    // ---- stage xs[b] fp32 -> fp16 LDS (RTNE casts) ----
    {
        const float4* src = (const float4*)(xs + (size_t)b * N_ * D_);
        #pragma unroll
        for (int u = 0; u < 8; ++u) {
            int q = t + 256 * u;              // 2048 float4
            float4 v = src[q];
            int row = q >> 6, col4 = q & 63;
            union { f16x2 h2[2]; uint64_t u64; } pk;
            pk.h2[0][0] = (_Float16)v.x; pk.h2[0][1] = (_Float16)v.y;
            pk.h2[1][0] = (_Float16)v.z; pk.h2[1][1] = (_Float16)v.w;
            *(uint64_t*)&xs_h[row * XBP + col4 * 4] = pk.u64;
        }
    }
    if (t < N_ * 3) rs_s[t] = rs[b * N_ * 3 + t];
    for (int i2 = t; i2 < N1 * N2; i2 += 256) nw2_s[i2] = nw2[i2];
    if (t < N2 * N3) nw3_s[t] = nw3[t];
    if (t < N2) nb2_s[t] = nb2[t];
    if (t < N3) nb3_s[t] = nb3[t];
    if (t < K_ * 3) co_s[t] = coords[t];
    __syncthreads();   // B1: xs_h + weights-in-LDS ready

    // ---- en layer 1 via MFMA: rows 16p..16p+15; 6 N-tiles over 4 waves ----
    #pragma unroll 1
    for (int e = wv; e < 6; e += 4) {
        int Nt = e;
        int n  = Nt * 16 + c;
        bool nok = (n < N1);
        float nb1v = nok ? nb1[n] : 0.f;
        f32x4 acc = {0.f, 0.f, 0.f, 0.f};
        for (int Kt = 0; Kt < 8; ++Kt) {
            FragU bfr; bfr.d = nw1f[(Nt * 8 + Kt) * 64 + l];
            f16x8 afr = *(const f16x8*)&xs_h[(p * 16 + c) * XBP + Kt * 32 + quad * 8];
            acc = __builtin_amdgcn_mfma_f32_16x16x32_f16(afr, bfr.v, acc, 0, 0, 0);
        }
        if (nok) {
            #pragma unroll
            for (int r2 = 0; r2 < 4; ++r2) {
                int m = quad * 4 + r2;             // local row 0..15
                h1e[m * HEP + n] = (_Float16)sspf(acc[r2] + nb1v);
            }
        }
    }
    __syncthreads();   // B2: h1e complete

    // ---- en layer 2 (VALU): 16 rows x 16 lanes, 2 cols each ----
    {
        const int r = t >> 4, s = t & 15;
        const int n0 = 2 * s;
        if (n0 < N2) {
            float a0 = 0.f, a1 = 0.f;
            const int rb = r * HEP;
            for (int kk = 0; kk < N1; ++kk) {
                float hv = (float)h1e[rb + kk];
                const float* wrow = nw2_s + kk * N2 + n0;
                a0 = fmaf(hv, wrow[0], a0);
                if (n0 + 1 < N2) a1 = fmaf(hv, wrow[1], a1);
            }
            h2e[r * 26 + n0] = sspf(a0 + nb2_s[n0]);
            if (n0 + 1 < N2) h2e[r * 26 + n0 + 1] = sspf(a1 + nb2_s[n0 + 1]);
        }
    }
    __syncthreads();   // B3: h2e complete

    // ---- en layer 3 + bf_nuc + cutoff (threads 0..127) ----
    if (t < 128) {
        const int r = t >> 3, s = t & 7;       // r local 0..15
        float w = nb3_s[s];
        const int rb = r * 26;
        #pragma unroll
        for (int kk = 0; kk < N2; ++kk)
            w = fmaf(h2e[rb + kk], nw3_s[kk * N3 + s], w);

        const int rg = p * 16 + r;
        float dx = rs_s[rg * 3 + 0] - co_s[s * 3 + 0];
        float dy = rs_s[rg * 3 + 1] - co_s[s * 3 + 1];
        float dz = rs_s[rg * 3 + 2] - co_s[s * 3 + 2];
        float cx = w * dx, cy = w * dy, cz = w * dz;
        #pragma unroll
        for (int m2 = 1; m2 < 8; m2 <<= 1) {
            cx += __shfl_xor(cx, m2);
            cy += __shfl_xor(cy, m2);
            cz += __shfl_xor(cz, m2);
        }
        float rr  = sqrtf(dx * dx + dy * dy + dz * dz);
        float xsc = 2.f * rr;                 // r / L, L = 0.5
        float cf  = (xsc < 0.5f) ? xsc * xsc * (6.f - 8.f * xsc + 3.f * xsc * xsc) : 1.f;
        #pragma unroll
        for (int m2 = 1; m2 < 8; m2 <<= 1) cf *= __shfl_xor(cf, m2);
        if (s == 0) {
            bfn_s[r * 3 + 0] = cx;
            bfn_s[r * 3 + 1] = cy;
            bfn_s[r * 3 + 2] = cz;
            cut_s[r] = cf;
        }
    }
    __syncthreads();   // B4: en done; union region now free for h1t

    // zero h1t cols 48..63 (read by layer-2 MFMA; B-side rows there are 0, but
    // A must be finite). Per-wave tile; same-wave ordering suffices.
    _Float16* myh1 = (_Float16*)(uni + wv * 16 * H1P * 2);
    *(uint64_t*)&myh1[c * H1P + 48 + quad * 4] = 0ull;

    // ---- ee main: 4 i per wave; h=0/1 -> j=0..15 / 16..31 ----
    #pragma unroll 1
    for (int q8 = 0; q8 < 4; ++q8) {
        const int il = wv + 4 * q8;            // i local 0..15
        const int i  = 16 * p + il;            // i global
        f32x4 acc[2][3];
        #pragma unroll
        for (int h = 0; h < 2; ++h)
            #pragma unroll
            for (int Nt = 0; Nt < 3; ++Nt) acc[h][Nt] = (f32x4){0.f, 0.f, 0.f, 0.f};

        #pragma unroll
        for (int Kt = 0; Kt < 8; ++Kt) {
            const int koff = Kt * 32 + quad * 8;
            f16x8 iv  = *(const f16x8*)&xs_h[i * XBP + koff];
            f16x8 jv0 = *(const f16x8*)&xs_h[c * XBP + koff];
            f16x8 jv1 = *(const f16x8*)&xs_h[(16 + c) * XBP + koff];
            f16x8 A0 = iv * jv0;               // 4x v_pk_mul_f16
            f16x8 A1 = iv * jv1;
            #pragma unroll
            for (int Nt = 0; Nt < 3; ++Nt) {
                acc[0][Nt] = __builtin_amdgcn_mfma_f32_16x16x32_f16(A0, b1f[Nt][Kt], acc[0][Nt], 0, 0, 0);
                acc[1][Nt] = __builtin_amdgcn_mfma_f32_16x16x32_f16(A1, b1f[Nt][Kt], acc[1][Nt], 0, 0, 0);
            }
        }

        // epilogue: h1 -> LDS layout swap -> layer2 MFMA -> layer3 -> w_s
        #pragma unroll
        for (int h = 0; h < 2; ++h) {
            #pragma unroll
            for (int Nt = 0; Nt < 3; ++Nt) {
                #pragma unroll
                for (int r2 = 0; r2 < 4; ++r2) {
                    float hv = sspf(acc[h][Nt][r2] + eb1v[Nt]);
                    myh1[(quad * 4 + r2) * H1P + Nt * 16 + c] = (_Float16)hv;
                }
            }
            f32x4 acc2 = {0.f, 0.f, 0.f, 0.f};
            #pragma unroll
            for (int Kt2 = 0; Kt2 < 2; ++Kt2) {
                f16x8 a2 = *(const f16x8*)&myh1[c * H1P + Kt2 * 32 + quad * 8];
                acc2 = __builtin_amdgcn_mfma_f32_16x16x32_f16(a2, b2f[Kt2], acc2, 0, 0, 0);
            }
            float wp[4];
            #pragma unroll
            for (int r2 = 0; r2 < 4; ++r2) wp[r2] = sspf(acc2[r2] + eb2v) * w3v;
            #pragma unroll
            for (int m2 = 1; m2 < 16; m2 <<= 1) {
                #pragma unroll
                for (int r2 = 0; r2 < 4; ++r2) wp[r2] += __shfl_xor(wp[r2], m2);
            }
            if (c == 0) {
                int Mt = 2 * il + h;
                float4* dst = (float4*)&w_s[Mt * 16 + quad * 4];
                *dst = make_float4(wp[0] + eb3v, wp[1] + eb3v, wp[2] + eb3v, wp[3] + eb3v);
            }
        }
    }
    __syncthreads();   // B5: w_s ready

    // ---- final: bf_elec contraction + combine + store (threads 0..127) ----
    if (t < 128) {
        const int il = t >> 3, si = t & 7;
        const int i  = 16 * p + il;
        const float4 wq = *(const float4*)&w_s[il * 32 + si * 4];
        const float rix = rs_s[i * 3 + 0], riy = rs_s[i * 3 + 1], riz = rs_s[i * 3 + 2];
        float cx = 0.f, cy = 0.f, cz = 0.f;
        const float wa[4] = {wq.x, wq.y, wq.z, wq.w};
        #pragma unroll
        for (int u = 0; u < 4; ++u) {
            int j = si * 4 + u;
            cx = fmaf(wa[u], rix - rs_s[j * 3 + 0], cx);
            cy = fmaf(wa[u], riy - rs_s[j * 3 + 1], cy);
            cz = fmaf(wa[u], riz - rs_s[j * 3 + 2], cz);
        }
        #pragma unroll
        for (int m2 = 1; m2 < 8; m2 <<= 1) {
            cx += __shfl_xor(cx, m2);
            cy += __shfl_xor(cy, m2);
            cz += __shfl_xor(cz, m2);
        }
        if (si < 3) {
            float bfe = (si == 0) ? cx : ((si == 1) ? cy : cz);
            float bfv = bfe + bfn_s[il * 3 + si];
            int idx = i * 3 + si;
            out[(size_t)b * (N_ * 3) + idx] =
                rs_s[idx] + 1e-4f * cut_s[il] * bfv;
        }
    }
}

extern "C" void kernel_launch(void* const* d_in, const int* in_sizes, int n_in,
                              void* d_out, int out_size, void* d_ws, size_t ws_size,
                              hipStream_t stream)
{
    const float* rs     = (const float*)d_in[0];
    const float* xs     = (const float*)d_in[1];
    const float* coords = (const float*)d_in[2];
    const float* ew1    = (const float*)d_in[3];
    const float* eb1    = (const float*)d_in[4];
    const float* ew2    = (const float*)d_in[5];
    const float* eb2    = (const float*)d_in[6];
    const float* ew3    = (const float*)d_in[7];
    const float* eb3    = (const float*)d_in[8];
    const float* nw1    = (const float*)d_in[9];
    const float* nb1    = (const float*)d_in[10];
    const float* nw2    = (const float*)d_in[11];
    const float* nb2    = (const float*)d_in[12];
    const float* nw3    = (const float*)d_in[13];
    const float* nb3    = (const float*)d_in[14];

    u32x4* ws   = (u32x4*)d_ws;
    u32x4* ew1f = ws;                  // 24*64 u32x4
    u32x4* nw1f = ws + 24 * 64;        // 48*64 u32x4
    u32x4* w2f  = ws + 72 * 64;        // 2*64 u32x4

    k_prep<<<19, 256, 0, stream>>>(ew1, ew2, nw1, ew1f, nw1f, w2f);
    k_fused<<<2 * B_, 256, 0, stream>>>(rs, xs, coords, ew1f, eb1, w2f, eb2, ew3, eb3,
                                        nw1f, nb1, nw2, nb2, nw3, nb3, (float*)d_out);
}

// Round 8
// 158.168 us; speedup vs baseline: 1.1959x; 1.1959x over previous
//
#include <hip/hip_runtime.h>
#include <stdint.h>

static constexpr int B_ = 512, N_ = 32, D_ = 256, K_ = 8;
static constexpr int E1 = 40, E2 = 6;          // ee MLP dims 256->40->6->1
static constexpr int N1 = 81, N2 = 25, N3 = 8; // en MLP dims 256->81->25->8
static constexpr int XBP = 264;                // xs_h row stride (f16), 528 B, 16B-aligned
static constexpr int H1P = 72;                 // h1t row stride (f16), 144 B, 16B-aligned
static constexpr int HEP = 88;                 // h1e row stride (f16)
static constexpr int EWT = 264;                // ew1T row stride (f16), 528 B, 16B-aligned
static constexpr int TKP = 40;                 // en tile k-stride (f16), 80 B, 16B-aligned
static constexpr float LN2f = 0.69314718055994530942f;

typedef float    f32x4 __attribute__((ext_vector_type(4)));
typedef _Float16 f16x8 __attribute__((ext_vector_type(8)));

__device__ __forceinline__ float sspf(float x) {
    float ax = fabsf(x);
    float e  = __expf(-ax);
    return fmaxf(x, 0.f) + __logf(1.f + e) - LN2f;
}

// single fused kernel; grid = B_ (one block per batch)
__global__ __launch_bounds__(256) void k_fused(
    const float* __restrict__ rs, const float* __restrict__ xs,
    const float* __restrict__ coords,
    const float* __restrict__ ew1, const float* __restrict__ eb1,
    const float* __restrict__ ew2, const float* __restrict__ eb2,
    const float* __restrict__ ew3, const float* __restrict__ eb3,
    const float* __restrict__ nw1, const float* __restrict__ nb1,
    const float* __restrict__ nw2, const float* __restrict__ nb2,
    const float* __restrict__ nw3, const float* __restrict__ nb3,
    float* __restrict__ out)
{
    __shared__ alignas(16) _Float16 xs_h[N_ * XBP];    // 16896 B
    __shared__ alignas(16) _Float16 wbuf[E1 * EWT];    // 21120 B: ew1T, then 2x en tiles
    __shared__ alignas(16) char uni[4 * 16 * H1P * 2]; // 9216 B: h1e+h2e, then h1t
    __shared__ float w_s[N_ * N_];                     // 4096 B, [2i+h][16] pair weights
    __shared__ float nw2_s[N1 * N2];                   // 8100 B
    __shared__ float nw3_s[N2 * N3];
    __shared__ float rs_s[N_ * 3];
    __shared__ float nb2_s[N2];
    __shared__ float nb3_s[N3];
    __shared__ float co_s[K_ * 3];
    __shared__ float bfn_s[N_ * 3];
    __shared__ float cut_s[N_];

    _Float16* h1e = (_Float16*)uni;                    // [32][HEP] f16 = 5632 B
    float*    h2e = (float*)(uni + N_ * HEP * 2);      // [32][26] f32 = 3328 B

    const int b = blockIdx.x, t = threadIdx.x;
    const int wv = t >> 6, l = t & 63, quad = l >> 4, c = l & 15;

    // ---- scalars + ee W2 frags from global (no LDS dep; issue early) ----
    f16x8 b2f[2];
    #pragma unroll
    for (int Kt = 0; Kt < 2; ++Kt) {
        union { uint32_t d[4]; f16x8 v; } f;
        #pragma unroll
        for (int d2 = 0; d2 < 4; ++d2) {
            int k0 = Kt * 32 + quad * 8 + 2 * d2;
            union { _Float16 h[2]; uint32_t u; } pk;
            pk.h[0] = (_Float16)((k0 < E1 && c < E2) ? ew2[k0 * E2 + c] : 0.f);
            pk.h[1] = (_Float16)((k0 + 1 < E1 && c < E2) ? ew2[(k0 + 1) * E2 + c] : 0.f);
            f.d[d2] = pk.u;
        }
        b2f[Kt] = f.v;
    }
    float eb1v[3];
    #pragma unroll
    for (int Nt = 0; Nt < 3; ++Nt) { int n = Nt * 16 + c; eb1v[Nt] = (n < E1) ? eb1[n] : 0.f; }
    const float eb2v = (c < E2) ? eb2[c] : 0.f;
    const float w3v  = (c < E2) ? ew3[c] : 0.f;
    const float eb3v = eb3[0];
    float nb1v[3];   // en layer-1 bias for this lane's 3 products
    #pragma unroll
    for (int e = 0; e < 3; ++e) {
        int p = 3 * wv + e, n = (p >> 1) * 16 + c;
        nb1v[e] = (n < N1) ? nb1[n] : 0.f;
    }

    // ---- stage xs[b] fp32 -> fp16 LDS ----
    {
        const float4* src = (const float4*)(xs + (size_t)b * N_ * D_);
        #pragma unroll
        for (int u = 0; u < 8; ++u) {
            int q = t + 256 * u;              // 2048 float4
            float4 v = src[q];
            int row = q >> 6, col4 = q & 63;
            union { _Float16 h[4]; uint64_t u64; } pk;
            pk.h[0] = (_Float16)v.x; pk.h[1] = (_Float16)v.y;
            pk.h[2] = (_Float16)v.z; pk.h[3] = (_Float16)v.w;
            *(uint64_t*)&xs_h[row * XBP + col4 * 4] = pk.u64;
        }
    }
    // ---- stage ew1 [256][40] -> ew1T [40 n][264 k] f16 (transposed) ----
    {
        const float4* src = (const float4*)ew1;   // 2560 float4
        #pragma unroll
        for (int u = 0; u < 10; ++u) {
            int q = t + 256 * u;
            float4 v = src[q];
            int k = q / 10, n0 = (q - 10 * k) * 4;
            wbuf[(n0 + 0) * EWT + k] = (_Float16)v.x;
            wbuf[(n0 + 1) * EWT + k] = (_Float16)v.y;
            wbuf[(n0 + 2) * EWT + k] = (_Float16)v.z;
            wbuf[(n0 + 3) * EWT + k] = (_Float16)v.w;
        }
    }
    if (t < N_ * 3) rs_s[t] = rs[b * N_ * 3 + t];
    for (int i2 = t; i2 < N1 * N2; i2 += 256) nw2_s[i2] = nw2[i2];
    if (t < N2 * N3) nw3_s[t] = nw3[t];
    if (t < N2) nb2_s[t] = nb2[t];
    if (t < N3) nb3_s[t] = nb3[t];
    if (t < K_ * 3) co_s[t] = coords[t];
    __syncthreads();   // B1: xs_h + ew1T + weights ready

    // ---- build ee W1 fragments from ew1T (24 ds_read_b128 per lane) ----
    f16x8 b1f[3][8];
    #pragma unroll
    for (int Nt = 0; Nt < 3; ++Nt) {
        int n = Nt * 16 + c;
        bool ok = (n < E1);
        int row = ok ? n : 0;
        #pragma unroll
        for (int Kt = 0; Kt < 8; ++Kt) {
            f16x8 v = *(const f16x8*)&wbuf[row * EWT + Kt * 32 + quad * 8];
            if (!ok) v = (f16x8)(_Float16)0.f;
            b1f[Nt][Kt] = v;
        }
    }
    __syncthreads();   // B2: ew1T reads done; wbuf reusable for en tiles

    // ---- en layer 1 via MFMA with double-buffered nw1 K-tiles ----
    // tile[Kt]: [96 n][TKP k] f16; base = wbuf + (Kt&1)*96*TKP (no LDS ptr array!)
    {
        f32x4 acc3[3];
        #pragma unroll
        for (int e = 0; e < 3; ++e) acc3[e] = (f32x4){0.f, 0.f, 0.f, 0.f};

        // stage tile 0
        {
            const float* wk = nw1;
            #pragma unroll
            for (int u = 0; u < 12; ++u) {
                int idx = t + 256 * u;        // 3072 = 32k x 96n
                int k = idx / 96, n = idx - 96 * k;
                float v = (n < N1) ? wk[k * N1 + n] : 0.f;
                wbuf[n * TKP + k] = (_Float16)v;
            }
        }
        __syncthreads();                      // B3: tile 0 ready
        #pragma unroll 1
        for (int Kt = 0; Kt < 8; ++Kt) {
            if (Kt < 7) {
                const float* wk = nw1 + ((Kt + 1) * 32) * N1;
                _Float16* dst = wbuf + ((Kt + 1) & 1) * (96 * TKP);
                #pragma unroll
                for (int u = 0; u < 12; ++u) {
                    int idx = t + 256 * u;
                    int k = idx / 96, n = idx - 96 * k;
                    float v = (n < N1) ? wk[k * N1 + n] : 0.f;
                    dst[n * TKP + k] = (_Float16)v;
                }
            }
            const _Float16* T = wbuf + (Kt & 1) * (96 * TKP);
            #pragma unroll
            for (int e = 0; e < 3; ++e) {
                int p = 3 * wv + e, Mt = p & 1, Nt = p >> 1;
                f16x8 A = *(const f16x8*)&xs_h[(Mt * 16 + c) * XBP + Kt * 32 + quad * 8];
                f16x8 Bf = *(const f16x8*)&T[(Nt * 16 + c) * TKP + quad * 8];
                acc3[e] = __builtin_amdgcn_mfma_f32_16x16x32_f16(A, Bf, acc3[e], 0, 0, 0);
            }
            __syncthreads();                  // B4..B11: frees cur tile, publishes next
        }
        // epilogue: bias + ssp -> h1e (f16)
        #pragma unroll
        for (int e = 0; e < 3; ++e) {
            int p = 3 * wv + e, Mt = p & 1, Nt = p >> 1;
            int n = Nt * 16 + c;
            if (n < N1) {
                #pragma unroll
                for (int r2 = 0; r2 < 4; ++r2) {
                    int m = Mt * 16 + quad * 4 + r2;
                    h1e[m * HEP + n] = (_Float16)sspf(acc3[e][r2] + nb1v[e]);
                }
            }
        }
    }
    __syncthreads();   // B12: h1e complete

    // ---- en layer 2 (VALU): 32 rows x 8 lanes, 3(+1) cols each ----
    {
        const int r = t >> 3, s = t & 7;
        const int n0 = 3 * s;
        float acc2[4] = {0.f, 0.f, 0.f, 0.f};
        const int rb = r * HEP;
        for (int kk = 0; kk < N1; ++kk) {
            float hv = (float)h1e[rb + kk];
            const float* wrow = nw2_s + kk * N2 + n0;
            #pragma unroll
            for (int u = 0; u < 4; ++u) acc2[u] = fmaf(hv, wrow[u], acc2[u]);
        }
        #pragma unroll
        for (int u = 0; u < 4; ++u) {
            int n = n0 + u;
            if (u < 3 || s == 7) h2e[r * 26 + n] = sspf(acc2[u] + nb2_s[n]);
        }
    }
    __syncthreads();   // B13: h2e complete

    // ---- en layer 3 + bf_nuc + cutoff (all 256 threads, 32 rows x 8 nuclei) ----
    {
        const int r = t >> 3, s = t & 7;
        float w = nb3_s[s];
        const int rb = r * 26;
        #pragma unroll
        for (int kk = 0; kk < N2; ++kk)
            w = fmaf(h2e[rb + kk], nw3_s[kk * N3 + s], w);

        float dx = rs_s[r * 3 + 0] - co_s[s * 3 + 0];
        float dy = rs_s[r * 3 + 1] - co_s[s * 3 + 1];
        float dz = rs_s[r * 3 + 2] - co_s[s * 3 + 2];
        float cx = w * dx, cy = w * dy, cz = w * dz;
        #pragma unroll
        for (int m2 = 1; m2 < 8; m2 <<= 1) {
            cx += __shfl_xor(cx, m2);
            cy += __shfl_xor(cy, m2);
            cz += __shfl_xor(cz, m2);
        }
        float rr  = sqrtf(dx * dx + dy * dy + dz * dz);
        float xsc = 2.f * rr;                 // r / L, L = 0.5
        float cf  = (xsc < 0.5f) ? xsc * xsc * (6.f - 8.f * xsc + 3.f * xsc * xsc) : 1.f;
        #pragma unroll
        for (int m2 = 1; m2 < 8; m2 <<= 1) cf *= __shfl_xor(cf, m2);
        if (s == 0) {
            bfn_s[r * 3 + 0] = cx;
            bfn_s[r * 3 + 1] = cy;
            bfn_s[r * 3 + 2] = cz;
            cut_s[r] = cf;
        }
    }
    __syncthreads();   // B14: en done; uni free for h1t

    // zero h1t cols 48..63 (A-operand pad for layer-2 MFMA must be finite)
    _Float16* myh1 = (_Float16*)(uni + wv * (16 * H1P * 2));
    *(uint64_t*)&myh1[c * H1P + 48 + quad * 4] = 0ull;

    // ---- ee main: 8 i per wave; h=0/1 -> j=0..15 / 16..31 ----
    #pragma unroll 1
    for (int q8 = 0; q8 < 8; ++q8) {
        const int i = wv + 4 * q8;
        f32x4 acc[2][3];
        #pragma unroll
        for (int h = 0; h < 2; ++h)
            #pragma unroll
            for (int Nt = 0; Nt < 3; ++Nt) acc[h][Nt] = (f32x4){0.f, 0.f, 0.f, 0.f};

        #pragma unroll
        for (int Kt = 0; Kt < 8; ++Kt) {
            const int koff = Kt * 32 + quad * 8;
            f16x8 iv  = *(const f16x8*)&xs_h[i * XBP + koff];
            f16x8 jv0 = *(const f16x8*)&xs_h[c * XBP + koff];
            f16x8 jv1 = *(const f16x8*)&xs_h[(16 + c) * XBP + koff];
            f16x8 A0 = iv * jv0;               // v_pk_mul_f16 x4
            f16x8 A1 = iv * jv1;
            #pragma unroll
            for (int Nt = 0; Nt < 3; ++Nt) {
                acc[0][Nt] = __builtin_amdgcn_mfma_f32_16x16x32_f16(A0, b1f[Nt][Kt], acc[0][Nt], 0, 0, 0);
                acc[1][Nt] = __builtin_amdgcn_mfma_f32_16x16x32_f16(A1, b1f[Nt][Kt], acc[1][Nt], 0, 0, 0);
            }
        }

        // epilogue: h1 -> LDS layout swap -> layer2 MFMA -> layer3 -> w_s
        #pragma unroll
        for (int h = 0; h < 2; ++h) {
            #pragma unroll
            for (int Nt = 0; Nt < 3; ++Nt) {
                #pragma unroll
                for (int r2 = 0; r2 < 4; ++r2) {
                    float hv = sspf(acc[h][Nt][r2] + eb1v[Nt]);
                    myh1[(quad * 4 + r2) * H1P + Nt * 16 + c] = (_Float16)hv;
                }
            }
            f32x4 acc2 = {0.f, 0.f, 0.f, 0.f};
            #pragma unroll
            for (int Kt2 = 0; Kt2 < 2; ++Kt2) {
                f16x8 a2 = *(const f16x8*)&myh1[c * H1P + Kt2 * 32 + quad * 8];
                acc2 = __builtin_amdgcn_mfma_f32_16x16x32_f16(a2, b2f[Kt2], acc2, 0, 0, 0);
            }
            float wp[4];
            #pragma unroll
            for (int r2 = 0; r2 < 4; ++r2) wp[r2] = sspf(acc2[r2] + eb2v) * w3v;
            #pragma unroll
            for (int m2 = 1; m2 < 16; m2 <<= 1) {
                #pragma unroll
                for (int r2 = 0; r2 < 4; ++r2) wp[r2] += __shfl_xor(wp[r2], m2);
            }
            if (c == 0) {
                int Mt = 2 * i + h;
                float4* dst = (float4*)&w_s[Mt * 16 + quad * 4];
                *dst = make_float4(wp[0] + eb3v, wp[1] + eb3v, wp[2] + eb3v, wp[3] + eb3v);
            }
        }
    }
    __syncthreads();   // B15: w_s ready

    // ---- final: bf_elec contraction + combine + store ----
    {
        const int i = t >> 3, si = t & 7;
        const float4 wq = *(const float4*)&w_s[i * 32 + si * 4];
        const float rix = rs_s[i * 3 + 0], riy = rs_s[i * 3 + 1], riz = rs_s[i * 3 + 2];
        float cx = 0.f, cy = 0.f, cz = 0.f;
        const float wa[4] = {wq.x, wq.y, wq.z, wq.w};
        #pragma unroll
        for (int u = 0; u < 4; ++u) {
            int j = si * 4 + u;
            cx = fmaf(wa[u], rix - rs_s[j * 3 + 0], cx);
            cy = fmaf(wa[u], riy - rs_s[j * 3 + 1], cy);
            cz = fmaf(wa[u], riz - rs_s[j * 3 + 2], cz);
        }
        #pragma unroll
        for (int m2 = 1; m2 < 8; m2 <<= 1) {
            cx += __shfl_xor(cx, m2);
            cy += __shfl_xor(cy, m2);
            cz += __shfl_xor(cz, m2);
        }
        if (si < 3) {
            float bfe = (si == 0) ? cx : ((si == 1) ? cy : cz);
            int idx = i * 3 + si;
            out[(size_t)b * (N_ * 3) + idx] =
                rs_s[idx] + 1e-4f * cut_s[i] * (bfe + bfn_s[idx]);
        }
    }
}

extern "C" void kernel_launch(void* const* d_in, const int* in_sizes, int n_in,
                              void* d_out, int out_size, void* d_ws, size_t ws_size,
                              hipStream_t stream)
{
    const float* rs     = (const float*)d_in[0];
    const float* xs     = (const float*)d_in[1];
    const float* coords = (const float*)d_in[2];
    const float* ew1    = (const float*)d_in[3];
    const float* eb1    = (const float*)d_in[4];
    const float* ew2    = (const float*)d_in[5];
    const float* eb2    = (const float*)d_in[6];
    const float* ew3    = (const float*)d_in[7];
    const float* eb3    = (const float*)d_in[8];
    const float* nw1    = (const float*)d_in[9];
    const float* nb1    = (const float*)d_in[10];
    const float* nw2    = (const float*)d_in[11];
    const float* nb2    = (const float*)d_in[12];
    const float* nw3    = (const float*)d_in[13];
    const float* nb3    = (const float*)d_in[14];

    k_fused<<<B_, 256, 0, stream>>>(rs, xs, coords, ew1, eb1, ew2, eb2, ew3, eb3,
                                    nw1, nb1, nw2, nb2, nw3, nb3, (float*)d_out);
}

// Round 9
// 154.143 us; speedup vs baseline: 1.2272x; 1.0261x over previous
//
#include <hip/hip_runtime.h>
#include <stdint.h>

static constexpr int B_ = 512, N_ = 32, D_ = 256, K_ = 8;
static constexpr int E1 = 40, E2 = 6;          // ee MLP dims 256->40->6->1
static constexpr int N1 = 81, N2 = 25, N3 = 8; // en MLP dims 256->81->25->8
static constexpr int XBP = 264;                // xs_h row stride (f16), 528 B, 16B-aligned
static constexpr int H1P = 72;                 // h1t row stride (f16), 144 B, 16B-aligned
static constexpr int HEP = 88;                 // h1e row stride (f16)
static constexpr int EWT = 264;                // ew1T row stride (f16), 528 B, 16B-aligned
static constexpr int TKP = 40;                 // en tile k-stride (f16), 80 B, 16B-aligned
static constexpr float LN2f  = 0.69314718055994530942f;
static constexpr float L2Ef  = 1.44269504088896340736f;

typedef float    f32x4 __attribute__((ext_vector_type(4)));
typedef _Float16 f16x8 __attribute__((ext_vector_type(8)));

// ssp(x) = log(0.5 e^x + 0.5) = ln2 * log2(0.5*2^(x*log2e) + 0.5)
// valid for |x| < ~80 (true here: pre-activations are O(1)); 5 VALU ops.
__device__ __forceinline__ float sspf(float x) {
    float t = __builtin_amdgcn_exp2f(x * L2Ef);
    return LN2f * __builtin_amdgcn_logf(fmaf(t, 0.5f, 0.5f));
}

// single fused kernel; grid = B_ (one block per batch), 512 threads (8 waves)
__global__ __launch_bounds__(512) void k_fused(
    const float* __restrict__ rs, const float* __restrict__ xs,
    const float* __restrict__ coords,
    const float* __restrict__ ew1, const float* __restrict__ eb1,
    const float* __restrict__ ew2, const float* __restrict__ eb2,
    const float* __restrict__ ew3, const float* __restrict__ eb3,
    const float* __restrict__ nw1, const float* __restrict__ nb1,
    const float* __restrict__ nw2, const float* __restrict__ nb2,
    const float* __restrict__ nw3, const float* __restrict__ nb3,
    float* __restrict__ out)
{
    __shared__ alignas(16) _Float16 xs_h[N_ * XBP];    // 16896 B
    __shared__ alignas(16) _Float16 wbuf[E1 * EWT];    // 21120 B: ew1T, then 2x en tiles
    __shared__ alignas(16) char uni[8 * 16 * H1P * 2]; // 18432 B: h1e+h2e, then h1t x8 waves
    __shared__ float w_s[N_ * N_];                     // 4096 B, [2i+h][16] pair weights
    __shared__ float nw2_s[N1 * N2];                   // 8100 B
    __shared__ float nw3_s[N2 * N3];
    __shared__ float rs_s[N_ * 3];
    __shared__ float nb2_s[N2];
    __shared__ float nb3_s[N3];
    __shared__ float co_s[K_ * 3];
    __shared__ float bfn_s[N_ * 3];
    __shared__ float cut_s[N_];

    _Float16* h1e = (_Float16*)uni;                    // [32][HEP] f16 = 5632 B
    float*    h2e = (float*)(uni + N_ * HEP * 2);      // [32][26] f32 = 3328 B

    const int b = blockIdx.x, t = threadIdx.x;
    const int wv = t >> 6, l = t & 63, quad = l >> 4, c = l & 15;

    // ---- scalars + ee W2 frags from global (no LDS dep; issue early) ----
    f16x8 b2f[2];
    #pragma unroll
    for (int Kt = 0; Kt < 2; ++Kt) {
        union { uint32_t d[4]; f16x8 v; } f;
        #pragma unroll
        for (int d2 = 0; d2 < 4; ++d2) {
            int k0 = Kt * 32 + quad * 8 + 2 * d2;
            union { _Float16 h[2]; uint32_t u; } pk;
            pk.h[0] = (_Float16)((k0 < E1 && c < E2) ? ew2[k0 * E2 + c] : 0.f);
            pk.h[1] = (_Float16)((k0 + 1 < E1 && c < E2) ? ew2[(k0 + 1) * E2 + c] : 0.f);
            f.d[d2] = pk.u;
        }
        b2f[Kt] = f.v;
    }
    float eb1v[3];
    #pragma unroll
    for (int Nt = 0; Nt < 3; ++Nt) { int n = Nt * 16 + c; eb1v[Nt] = (n < E1) ? eb1[n] : 0.f; }
    const float eb2v = (c < E2) ? eb2[c] : 0.f;
    const float w3v  = (c < E2) ? ew3[c] : 0.f;
    const float eb3v = eb3[0];
    float nb1v[2];   // en layer-1 bias for this lane's products p = wv + 8e
    #pragma unroll
    for (int e = 0; e < 2; ++e) {
        int p = wv + 8 * e, n = (p >> 1) * 16 + c;
        nb1v[e] = (p < 12 && n < N1) ? nb1[n] : 0.f;
    }

    // ---- stage xs[b] fp32 -> fp16 LDS ----
    {
        const float4* src = (const float4*)(xs + (size_t)b * N_ * D_);
        #pragma unroll
        for (int u = 0; u < 4; ++u) {
            int q = t + 512 * u;              // 2048 float4
            float4 v = src[q];
            int row = q >> 6, col4 = q & 63;
            union { _Float16 h[4]; uint64_t u64; } pk;
            pk.h[0] = (_Float16)v.x; pk.h[1] = (_Float16)v.y;
            pk.h[2] = (_Float16)v.z; pk.h[3] = (_Float16)v.w;
            *(uint64_t*)&xs_h[row * XBP + col4 * 4] = pk.u64;
        }
    }
    // ---- stage ew1 [256][40] -> ew1T [40 n][264 k] f16 (transposed) ----
    {
        const float4* src = (const float4*)ew1;   // 2560 float4
        #pragma unroll
        for (int u = 0; u < 5; ++u) {
            int q = t + 512 * u;
            float4 v = src[q];
            int k = q / 10, n0 = (q - 10 * k) * 4;
            wbuf[(n0 + 0) * EWT + k] = (_Float16)v.x;
            wbuf[(n0 + 1) * EWT + k] = (_Float16)v.y;
            wbuf[(n0 + 2) * EWT + k] = (_Float16)v.z;
            wbuf[(n0 + 3) * EWT + k] = (_Float16)v.w;
        }
    }
    if (t < N_ * 3) rs_s[t] = rs[b * N_ * 3 + t];
    for (int i2 = t; i2 < N1 * N2; i2 += 512) nw2_s[i2] = nw2[i2];
    if (t < N2 * N3) nw3_s[t] = nw3[t];
    if (t < N2) nb2_s[t] = nb2[t];
    if (t < N3) nb3_s[t] = nb3[t];
    if (t < K_ * 3) co_s[t] = coords[t];
    __syncthreads();   // B1: xs_h + ew1T + weights ready

    // ---- build ee W1 fragments from ew1T (24 ds_read_b128 per lane) ----
    f16x8 b1f[3][8];
    #pragma unroll
    for (int Nt = 0; Nt < 3; ++Nt) {
        int n = Nt * 16 + c;
        bool ok = (n < E1);
        int row = ok ? n : 0;
        #pragma unroll
        for (int Kt = 0; Kt < 8; ++Kt) {
            f16x8 v = *(const f16x8*)&wbuf[row * EWT + Kt * 32 + quad * 8];
            if (!ok) v = (f16x8)(_Float16)0.f;
            b1f[Nt][Kt] = v;
        }
    }
    __syncthreads();   // B2: ew1T reads done; wbuf reusable for en tiles

    // ---- en layer 1 via MFMA with double-buffered nw1 K-tiles ----
    // tile: [96 n][TKP k] f16; lanes map k-consecutive -> conflict-free LDS writes
    {
        f32x4 acc3[2];
        #pragma unroll
        for (int e = 0; e < 2; ++e) acc3[e] = (f32x4){0.f, 0.f, 0.f, 0.f};

        // stage tile 0
        {
            const float* wk = nw1;
            #pragma unroll
            for (int u = 0; u < 6; ++u) {
                int idx = t + 512 * u;        // 3072 = 96n x 32k
                int n = idx >> 5, k = idx & 31;
                float v = (n < N1) ? wk[k * N1 + n] : 0.f;
                wbuf[n * TKP + k] = (_Float16)v;
            }
        }
        __syncthreads();                      // B3: tile 0 ready
        #pragma unroll 1
        for (int Kt = 0; Kt < 8; ++Kt) {
            if (Kt < 7) {
                const float* wk = nw1 + ((Kt + 1) * 32) * N1;
                _Float16* dst = wbuf + ((Kt + 1) & 1) * (96 * TKP);
                #pragma unroll
                for (int u = 0; u < 6; ++u) {
                    int idx = t + 512 * u;
                    int n = idx >> 5, k = idx & 31;
                    float v = (n < N1) ? wk[k * N1 + n] : 0.f;
                    dst[n * TKP + k] = (_Float16)v;
                }
            }
            const _Float16* T = wbuf + (Kt & 1) * (96 * TKP);
            #pragma unroll
            for (int e = 0; e < 2; ++e) {
                int p = wv + 8 * e;
                if (p < 12) {
                    int Mt = p & 1, Nt = p >> 1;
                    f16x8 A  = *(const f16x8*)&xs_h[(Mt * 16 + c) * XBP + Kt * 32 + quad * 8];
                    f16x8 Bf = *(const f16x8*)&T[(Nt * 16 + c) * TKP + quad * 8];
                    acc3[e] = __builtin_amdgcn_mfma_f32_16x16x32_f16(A, Bf, acc3[e], 0, 0, 0);
                }
            }
            __syncthreads();                  // B4..B11: frees cur tile, publishes next
        }
        // epilogue: bias + ssp -> h1e (f16)
        #pragma unroll
        for (int e = 0; e < 2; ++e) {
            int p = wv + 8 * e;
            if (p < 12) {
                int Mt = p & 1, Nt = p >> 1;
                int n = Nt * 16 + c;
                if (n < N1) {
                    #pragma unroll
                    for (int r2 = 0; r2 < 4; ++r2) {
                        int m = Mt * 16 + quad * 4 + r2;
                        h1e[m * HEP + n] = (_Float16)sspf(acc3[e][r2] + nb1v[e]);
                    }
                }
            }
        }
    }
    __syncthreads();   // B12: h1e complete

    // ---- en layer 2 (VALU): 32 rows x 16 lanes, 2 cols each ----
    {
        const int r = t >> 4, s = t & 15;
        const int n0 = 2 * s;
        if (n0 < N2) {
            float a0 = 0.f, a1 = 0.f;
            const int rb = r * HEP;
            for (int kk = 0; kk < N1; ++kk) {
                float hv = (float)h1e[rb + kk];
                const float* wrow = nw2_s + kk * N2 + n0;
                a0 = fmaf(hv, wrow[0], a0);
                if (n0 + 1 < N2) a1 = fmaf(hv, wrow[1], a1);
            }
            h2e[r * 26 + n0] = sspf(a0 + nb2_s[n0]);
            if (n0 + 1 < N2) h2e[r * 26 + n0 + 1] = sspf(a1 + nb2_s[n0 + 1]);
        }
    }
    __syncthreads();   // B13: h2e complete

    // ---- en layer 3 + bf_nuc + cutoff (threads 0..255: 32 rows x 8 nuclei) ----
    if (t < 256) {
        const int r = t >> 3, s = t & 7;
        float w = nb3_s[s];
        const int rb = r * 26;
        #pragma unroll
        for (int kk = 0; kk < N2; ++kk)
            w = fmaf(h2e[rb + kk], nw3_s[kk * N3 + s], w);

        float dx = rs_s[r * 3 + 0] - co_s[s * 3 + 0];
        float dy = rs_s[r * 3 + 1] - co_s[s * 3 + 1];
        float dz = rs_s[r * 3 + 2] - co_s[s * 3 + 2];
        float cx = w * dx, cy = w * dy, cz = w * dz;
        #pragma unroll
        for (int m2 = 1; m2 < 8; m2 <<= 1) {
            cx += __shfl_xor(cx, m2);
            cy += __shfl_xor(cy, m2);
            cz += __shfl_xor(cz, m2);
        }
        float rr  = sqrtf(dx * dx + dy * dy + dz * dz);
        float xsc = 2.f * rr;                 // r / L, L = 0.5
        float cf  = (xsc < 0.5f) ? xsc * xsc * (6.f - 8.f * xsc + 3.f * xsc * xsc) : 1.f;
        #pragma unroll
        for (int m2 = 1; m2 < 8; m2 <<= 1) cf *= __shfl_xor(cf, m2);
        if (s == 0) {
            bfn_s[r * 3 + 0] = cx;
            bfn_s[r * 3 + 1] = cy;
            bfn_s[r * 3 + 2] = cz;
            cut_s[r] = cf;
        }
    }
    __syncthreads();   // B14: en done; uni free for h1t

    // zero h1t cols 48..63 (A-operand pad for layer-2 MFMA must be finite)
    _Float16* myh1 = (_Float16*)(uni + wv * (16 * H1P * 2));
    *(uint64_t*)&myh1[c * H1P + 48 + quad * 4] = 0ull;

    // ---- ee main: 4 i per wave; h=0/1 -> j=0..15 / 16..31 ----
    #pragma unroll 1
    for (int q8 = 0; q8 < 4; ++q8) {
        const int i = wv + 8 * q8;
        f32x4 acc[2][3];
        #pragma unroll
        for (int h = 0; h < 2; ++h)
            #pragma unroll
            for (int Nt = 0; Nt < 3; ++Nt) acc[h][Nt] = (f32x4){0.f, 0.f, 0.f, 0.f};

        #pragma unroll
        for (int Kt = 0; Kt < 8; ++Kt) {
            const int koff = Kt * 32 + quad * 8;
            f16x8 iv  = *(const f16x8*)&xs_h[i * XBP + koff];
            f16x8 jv0 = *(const f16x8*)&xs_h[c * XBP + koff];
            f16x8 jv1 = *(const f16x8*)&xs_h[(16 + c) * XBP + koff];
            f16x8 A0 = iv * jv0;               // v_pk_mul_f16 x4
            f16x8 A1 = iv * jv1;
            #pragma unroll
            for (int Nt = 0; Nt < 3; ++Nt) {
                acc[0][Nt] = __builtin_amdgcn_mfma_f32_16x16x32_f16(A0, b1f[Nt][Kt], acc[0][Nt], 0, 0, 0);
                acc[1][Nt] = __builtin_amdgcn_mfma_f32_16x16x32_f16(A1, b1f[Nt][Kt], acc[1][Nt], 0, 0, 0);
            }
        }

        // epilogue: h1 -> LDS layout swap -> layer2 MFMA -> layer3 -> w_s
        #pragma unroll
        for (int h = 0; h < 2; ++h) {
            #pragma unroll
            for (int Nt = 0; Nt < 3; ++Nt) {
                #pragma unroll
                for (int r2 = 0; r2 < 4; ++r2) {
                    float hv = sspf(acc[h][Nt][r2] + eb1v[Nt]);
                    myh1[(quad * 4 + r2) * H1P + Nt * 16 + c] = (_Float16)hv;
                }
            }
            f32x4 acc2 = {0.f, 0.f, 0.f, 0.f};
            #pragma unroll
            for (int Kt2 = 0; Kt2 < 2; ++Kt2) {
                f16x8 a2 = *(const f16x8*)&myh1[c * H1P + Kt2 * 32 + quad * 8];
                acc2 = __builtin_amdgcn_mfma_f32_16x16x32_f16(a2, b2f[Kt2], acc2, 0, 0, 0);
            }
            float wp[4];
            #pragma unroll
            for (int r2 = 0; r2 < 4; ++r2) wp[r2] = sspf(acc2[r2] + eb2v) * w3v;
            #pragma unroll
            for (int m2 = 1; m2 < 16; m2 <<= 1) {
                #pragma unroll
                for (int r2 = 0; r2 < 4; ++r2) wp[r2] += __shfl_xor(wp[r2], m2);
            }
            if (c == 0) {
                int Mt = 2 * i + h;
                float4* dst = (float4*)&w_s[Mt * 16 + quad * 4];
                *dst = make_float4(wp[0] + eb3v, wp[1] + eb3v, wp[2] + eb3v, wp[3] + eb3v);
            }
        }
    }
    __syncthreads();   // B15: w_s ready

    // ---- final: bf_elec contraction + combine + store (threads 0..255) ----
    if (t < 256) {
        const int i = t >> 3, si = t & 7;
        const float4 wq = *(const float4*)&w_s[i * 32 + si * 4];
        const float rix = rs_s[i * 3 + 0], riy = rs_s[i * 3 + 1], riz = rs_s[i * 3 + 2];
        float cx = 0.f, cy = 0.f, cz = 0.f;
        const float wa[4] = {wq.x, wq.y, wq.z, wq.w};
        #pragma unroll
        for (int u = 0; u < 4; ++u) {
            int j = si * 4 + u;
            cx = fmaf(wa[u], rix - rs_s[j * 3 + 0], cx);
            cy = fmaf(wa[u], riy - rs_s[j * 3 + 1], cy);
            cz = fmaf(wa[u], riz - rs_s[j * 3 + 2], cz);
        }
        #pragma unroll
        for (int m2 = 1; m2 < 8; m2 <<= 1) {
            cx += __shfl_xor(cx, m2);
            cy += __shfl_xor(cy, m2);
            cz += __shfl_xor(cz, m2);
        }
        if (si < 3) {
            float bfe = (si == 0) ? cx : ((si == 1) ? cy : cz);
            int idx = i * 3 + si;
            out[(size_t)b * (N_ * 3) + idx] =
                rs_s[idx] + 1e-4f * cut_s[i] * (bfe + bfn_s[idx]);
        }
    }
}

extern "C" void kernel_launch(void* const* d_in, const int* in_sizes, int n_in,
                              void* d_out, int out_size, void* d_ws, size_t ws_size,
                              hipStream_t stream)
{
    const float* rs     = (const float*)d_in[0];
    const float* xs     = (const float*)d_in[1];
    const float* coords = (const float*)d_in[2];
    const float* ew1    = (const float*)d_in[3];
    const float* eb1    = (const float*)d_in[4];
    const float* ew2    = (const float*)d_in[5];
    const float* eb2    = (const float*)d_in[6];
    const float* ew3    = (const float*)d_in[7];
    const float* eb3    = (const float*)d_in[8];
    const float* nw1    = (const float*)d_in[9];
    const float* nb1    = (const float*)d_in[10];
    const float* nw2    = (const float*)d_in[11];
    const float* nb2    = (const float*)d_in[12];
    const float* nw3    = (const float*)d_in[13];
    const float* nb3    = (const float*)d_in[14];

    k_fused<<<B_, 512, 0, stream>>>(rs, xs, coords, ew1, eb1, ew2, eb2, ew3, eb3,
                                    nw1, nb1, nw2, nb2, nw3, nb3, (float*)d_out);
}